// Round 7
// baseline (275.238 us; speedup 1.0000x reference)
//
#include <hip/hip_runtime.h>
#include <hip/hip_bf16.h>

#define B_ 2
#define T_ 2048
#define D_ 2048
#define NH_ 16
#define NKV_ 4
#define HD_ 128

using bf16 = __bf16;
using bf16x8 = __attribute__((ext_vector_type(8))) __bf16;
using bf16x4 = __attribute__((ext_vector_type(4))) __bf16;
using f32x4 = __attribute__((ext_vector_type(4))) float;

__device__ __forceinline__ void gld_lds16(bf16* lds, const bf16* g) {
  __builtin_amdgcn_global_load_lds(
      (const __attribute__((address_space(1))) void*)g,
      (__attribute__((address_space(3))) void*)lds, 16, 0, 0);
}

// ---------------- fused f32 -> bf16 convert (all 5 tensors, 1 launch) ---------
// segments (in 256-thread blocks of float4): x 8192 | wq 4096 | wk 1024 | wv 1024 | wo 4096
__global__ __launch_bounds__(256) void cvt_all(const float* __restrict__ x,
                                               const float* __restrict__ wq,
                                               const float* __restrict__ wk,
                                               const float* __restrict__ wv,
                                               const float* __restrict__ wo,
                                               bf16* __restrict__ xb,
                                               bf16* __restrict__ wqkvb,
                                               bf16* __restrict__ wob) {
  const int bid = blockIdx.x;
  const float* src;
  bf16* dst;
  int base;
  if (bid < 8192)       { src = x;  dst = xb;              base = bid; }
  else if (bid < 12288) { src = wq; dst = wqkvb;           base = bid - 8192; }
  else if (bid < 13312) { src = wk; dst = wqkvb + 4194304; base = bid - 12288; }
  else if (bid < 14336) { src = wv; dst = wqkvb + 5242880; base = bid - 13312; }
  else                  { src = wo; dst = wob;             base = bid - 14336; }
  const int i = base * 256 + threadIdx.x;
  float4 v = ((const float4*)src)[i];
  bf16x4 o;
  o[0] = (bf16)v.x; o[1] = (bf16)v.y; o[2] = (bf16)v.z; o[3] = (bf16)v.w;
  ((bf16x4*)dst)[i] = o;
}

// ---------------- GEMM: C[M,N] = A[M,K] * Bt[N,K]^T ----------------
// 128x128 tile, BK=32, 256 threads (4 waves, 2x2), mfma 16x16x32 bf16.
// Triple-buffered LDS (48KB) + counted vmcnt(4) + raw s_barrier (1/K-step).
// Stage t+2 after barrier t; target buf (t-1)%3 safe (readers retired before
// the barrier). vmcnt(4) drains only stage(t), keeps stage(t+1) in flight.
// XCD-aware bijective block swizzle (grid size must be %8==0 — it is).
template<typename OutT>
__global__ __launch_bounds__(256) void gemm_bt(const bf16* __restrict__ A,
                                               const bf16* __restrict__ Bt,
                                               OutT* __restrict__ C,
                                               int M, int N, int K) {
  __shared__ bf16 As[3][128 * 32];
  __shared__ bf16 Bs[3][128 * 32];
  const int tid = threadIdx.x;
  const int wid = tid >> 6;
  const int lane = tid & 63;
  const int g = lane >> 4, r = lane & 15;
  const int wm = wid >> 1, wn = wid & 1;
  const int gx = gridDim.x;
  const int nwg = gx * gridDim.y;
  const int flat = blockIdx.y * gx + blockIdx.x;
  const int swz = (flat & 7) * (nwg >> 3) + (flat >> 3);
  const long bm = (long)(swz / gx) * 128, bn = (long)(swz % gx) * 128;
  f32x4 acc[4][4] = {};
  const int NT = K >> 5;

  auto stage = [&](int buf, int k0) {
    for (int c = 0; c < 2; ++c) {
      int ch = wid * 2 + c;
      int row = ch * 16 + (lane >> 2);
      int col = (lane & 3) * 8;
      gld_lds16(&As[buf][ch * 512], A + (bm + row) * K + k0 + col);
      gld_lds16(&Bs[buf][ch * 512], Bt + (bn + row) * K + k0 + col);
    }
  };

  stage(0, 0);
  stage(1, 32);
  for (int t = 0; t < NT; ++t) {
    if (t + 1 < NT)
      asm volatile("s_waitcnt vmcnt(4)" ::: "memory");  // stage(t) done, stage(t+1) in flight
    else
      asm volatile("s_waitcnt vmcnt(0)" ::: "memory");
    __builtin_amdgcn_s_barrier();
    if (t + 2 < NT) stage((t + 2) % 3, (t + 2) * 32);
    const bf16* as = As[t % 3];
    const bf16* bs = Bs[t % 3];
    bf16x8 af[4], bfr[4];
    for (int m = 0; m < 4; ++m)
      af[m] = *(const bf16x8*)(as + (wm * 64 + m * 16 + r) * 32 + g * 8);
    for (int n = 0; n < 4; ++n)
      bfr[n] = *(const bf16x8*)(bs + (wn * 64 + n * 16 + r) * 32 + g * 8);
    for (int m = 0; m < 4; ++m)
      for (int n = 0; n < 4; ++n)
        acc[m][n] = __builtin_amdgcn_mfma_f32_16x16x32_bf16(af[m], bfr[n], acc[m][n], 0, 0, 0);
  }

  for (int m = 0; m < 4; ++m)
    for (int n = 0; n < 4; ++n)
      for (int e = 0; e < 4; ++e) {
        long row = bm + wm * 64 + m * 16 + g * 4 + e;
        long col = bn + wn * 64 + n * 16 + r;
        C[row * N + col] = (OutT)acc[m][n][e];
      }
}

// ---------------- fused RMSNorm + RoPE for Q and K (one launch) ----------------
// blocks [0,16384): Q rows; [16384,20480): K rows.
__global__ __launch_bounds__(256) void norm_rope_qk(const bf16* __restrict__ qkv,
                                                    const float* __restrict__ qw,
                                                    const float* __restrict__ kw,
                                                    bf16* __restrict__ Qb,
                                                    bf16* __restrict__ Kb) {
  const int lane = threadIdx.x & 63;
  const int rloc = threadIdx.x >> 6;
  const int bid = blockIdx.x;
  const int IS_K = bid >= 16384;
  const int NHH = IS_K ? NKV_ : NH_;
  const int COFF = IS_K ? 2048 : 0;
  const float* w = IS_K ? kw : qw;
  const long rid = (long)(IS_K ? bid - 16384 : bid) * 4 + rloc;
  const int h = (int)(rid % NHH);
  const long bt = rid / NHH;  // b*T + t
  const int t = (int)(bt % T_);
  const bf16* src = qkv + bt * 3072 + COFF + h * HD_;
  float v0 = (float)src[lane];
  float v1 = (float)src[lane + 64];
  float ss = v0 * v0 + v1 * v1;
  for (int o = 1; o < 64; o <<= 1) ss += __shfl_xor(ss, o, 64);
  float inv = rsqrtf(ss * (1.f / HD_) + 1e-6f);
  float n0 = v0 * inv * w[lane];
  float n1 = v1 * inv * w[lane + 64];
  float ang = (float)t * exp2f((float)lane * (-13.287712379549449f / 64.f));
  float sv, cv;
  __sincosf(ang, &sv, &cv);
  float o0 = n0 * cv - n1 * sv;
  float o1 = n1 * cv + n0 * sv;
  bf16* dst;
  if (IS_K) {
    long b = bt / T_;
    dst = Kb + ((b * NKV_ + h) * (long)T_ + t) * HD_;  // [B][NKV][T][HD]
  } else {
    dst = Qb + (bt * NH_ + h) * HD_;  // [B*T][NH*HD]
  }
  dst[lane] = (bf16)o0;
  dst[lane + 64] = (bf16)o1;
}

// ---------------- V transpose: QKV[.., 2560+kv*128+d] -> [B][NKV][HD][T] ----------------
__global__ __launch_bounds__(256) void vpack(const bf16* __restrict__ qkv,
                                             bf16* __restrict__ Vt) {
  __shared__ float tile[64][65];
  const int tt = blockIdx.x;
  const int dd = blockIdx.y & 1;
  const int bkv = blockIdx.y >> 1;
  const long b = bkv >> 2;
  const int kv = bkv & 3;
  const int t0 = tt * 64, d0 = dd * 64;
  for (int i = 0; i < 2; ++i) {
    int row = i * 32 + (threadIdx.x >> 3);
    int c8 = (threadIdx.x & 7) * 8;
    bf16x8 v = *(const bf16x8*)&qkv[(b * T_ + t0 + row) * 3072 + 2560 + kv * HD_ + d0 + c8];
    for (int j = 0; j < 8; ++j) tile[row][c8 + j] = (float)v[j];
  }
  __syncthreads();
  for (int i = 0; i < 2; ++i) {
    int drow = i * 32 + (threadIdx.x >> 3);
    int tc8 = (threadIdx.x & 7) * 8;
    bf16x8 o;
    for (int j = 0; j < 8; ++j) o[j] = (bf16)tile[tc8 + j][drow];
    *(bf16x8*)&Vt[((b * NKV_ + kv) * (long)HD_ + d0 + drow) * T_ + t0 + tc8] = o;
  }
}

// ---------------- causal GQA flash attention (swapped QK^T, per-lane softmax) ----
// Round 7: LDS-traffic halving. 4 waves / 128 q-rows per block; each wave
// owns TWO 16-row q-fragments (A at wid*32, B at wid*32+16). Every K/V LDS
// read (bk, bv) now feeds two MFMAs (one per fragment) -> block LDS reads
// per k-tile drop 272 -> 144 (the round-4 structure spent ~46us of 78.5 in
// the LDS pipe). The two fragments' softmax chains are fully independent ->
// 2x intra-wave ILP, compensating 8 waves/CU (round-3's failure was halved
// waves at CONSTANT per-wave ILP). MFMA totals, staging (round-3's verified
// 4-chunk variant), barriers, swizzles, pairing all unchanged.
// Anti-correlated qt pairing: co-resident pair (i, i+256) = same (x,y),
// opposite z; qt = z ? x : 15-x -> uniform 34 k-tile units per CU.
__global__ __launch_bounds__(256) void flash_attn(const bf16* __restrict__ Q,
                                                  const bf16* __restrict__ K,
                                                  const bf16* __restrict__ V,
                                                  bf16* __restrict__ O) {
  __shared__ bf16 Ks[2][64 * 128];   // [k][d], swizzled
  __shared__ bf16 Vs[2][128 * 64];   // [d][k], swizzled
  __shared__ bf16 Ps[8][16 * 64];    // [wave*2+frag] P tile [q][k], swizzled
  const int h = blockIdx.y, b = blockIdx.z;
  const int qt = b ? blockIdx.x : (gridDim.x - 1) - blockIdx.x;  // pair long+short per CU
  const int kv = h >> 2;
  const int tid = threadIdx.x, wid = tid >> 6, lane = tid & 63;
  const int g = lane >> 4, r = lane & 15;
  const int q0 = qt * 128;
  const int qbaseA = q0 + wid * 32;     // wave-uniform
  const int qbaseB = qbaseA + 16;
  const int qA = qbaseA + r;            // fragment A q-row (softmax ownership)
  const int qB = qbaseB + r;            // fragment B q-row

  bf16x8 aqA[4], aqB[4];
  const bf16* qpA = Q + ((long)(b * T_ + qA)) * (NH_ * HD_) + h * HD_;
  const bf16* qpB = Q + ((long)(b * T_ + qB)) * (NH_ * HD_) + h * HD_;
  for (int kk = 0; kk < 4; ++kk) {
    aqA[kk] = *(const bf16x8*)(qpA + kk * 32 + g * 8);
    aqB[kk] = *(const bf16x8*)(qpB + kk * 32 + g * 8);
  }

  f32x4 oaccA[8] = {}, oaccB[8] = {};
  float mA = -1e30f, lA = 0.f, mB = -1e30f, lB = 0.f;

  const bf16* Kbase = K + ((long)(b * NKV_ + kv)) * T_ * HD_;
  const bf16* Vbase = V + ((long)(b * NKV_ + kv)) * (long)HD_ * T_;
  const int nkt = 2 * qt + 2;

  // stage K (16 chunks of 1KB) + V^T (16 chunks): 4+4 chunks per wave
  auto stageKV = [&](int buf, int k0) {
    for (int c = 0; c < 4; ++c) {
      int ch = wid * 4 + c;
      {
        int row = ch * 4 + (lane >> 4);
        int srccol = ((lane & 15) ^ (row & 7)) * 8;
        gld_lds16(&Ks[buf][ch * 512], Kbase + (long)(k0 + row) * HD_ + srccol);
      }
      {
        int row = ch * 8 + (lane >> 3);
        int srccol = ((lane & 7) ^ (row & 7)) * 8;
        gld_lds16(&Vs[buf][ch * 512], Vbase + (long)row * T_ + k0 + srccol);
      }
    }
  };

  const float scale = 0.088388347648318447f;  // 1/sqrt(128)

  stageKV(0, 0);
  for (int kt = 0; kt < nkt; ++kt) {
    const int k0 = kt * 64;
    const int cur = kt & 1;
    if (kt + 1 < nkt) {
      stageKV(cur ^ 1, k0 + 64);
      asm volatile("s_waitcnt vmcnt(8)" ::: "memory");  // drain current tile only
    } else {
      asm volatile("s_waitcnt vmcnt(0)" ::: "memory");
    }
    __builtin_amdgcn_s_barrier();

    // S^T = K * Q^T for both fragments: one bk read feeds two MFMAs
    f32x4 sA[4] = {}, sB[4] = {};
    __builtin_amdgcn_s_setprio(1);
    for (int n = 0; n < 4; ++n)
      for (int kk = 0; kk < 4; ++kk) {
        int row = n * 16 + r;
        bf16x8 bk = *(const bf16x8*)(&Ks[cur][row * 128 + (((kk * 4 + g) ^ (row & 7)) * 8)]);
        sA[n] = __builtin_amdgcn_mfma_f32_16x16x32_bf16(bk, aqA[kk], sA[n], 0, 0, 0);
        sB[n] = __builtin_amdgcn_mfma_f32_16x16x32_bf16(bk, aqB[kk], sB[n], 0, 0, 0);
      }
    __builtin_amdgcn_s_setprio(0);

    // per-lane softmax over 16 k-values, one independent chain per fragment
    auto softmax_half = [&](f32x4 (&s)[4], float& m_run, float& l_run,
                            const int qq, const int qbase, bf16* ps,
                            f32x4 (&oacc)[8]) {
      const bool domask = (k0 + 63 > qbase);  // wave-uniform
      float mx = -1e30f;
      if (domask) {
        for (int n = 0; n < 4; ++n) {
          const int km = k0 + n * 16 + g * 4;
          for (int e = 0; e < 4; ++e) {
            float v = s[n][e] * scale;
            if (km + e > qq) v = -1e30f;
            s[n][e] = v;
            mx = fmaxf(mx, v);
          }
        }
      } else {
        for (int n = 0; n < 4; ++n)
          for (int e = 0; e < 4; ++e) {
            float v = s[n][e] * scale;
            s[n][e] = v;
            mx = fmaxf(mx, v);
          }
      }
      mx = fmaxf(mx, __shfl_xor(mx, 16, 64));
      mx = fmaxf(mx, __shfl_xor(mx, 32, 64));
      float mnew = fmaxf(m_run, mx);
      float alpha = __expf(m_run - mnew);
      float ls = 0.f;
      for (int n = 0; n < 4; ++n) {
        bf16x4 pb;
        for (int e = 0; e < 4; ++e) {
          float p = __expf(s[n][e] - mnew);
          ls += p;
          pb[e] = (bf16)p;
        }
        int c = n * 2 + (g >> 1);
        *(bf16x4*)(&ps[r * 64 + ((c ^ (r & 7)) * 8) + (g & 1) * 4]) = pb;
      }
      ls += __shfl_xor(ls, 16, 64);
      ls += __shfl_xor(ls, 32, 64);
      m_run = mnew;
      l_run = l_run * alpha + ls;
      // broadcast alpha to oacc row layout (row = g*4+e held by lane with r==row)
      float al[4];
      for (int e = 0; e < 4; ++e)
        al[e] = __shfl(alpha, (lane & 48) | (g * 4 + e), 64);
      for (int dt = 0; dt < 8; ++dt)
        for (int e = 0; e < 4; ++e) oacc[dt][e] *= al[e];
    };
    softmax_half(sA, mA, lA, qA, qbaseA, &Ps[wid * 2][0], oaccA);
    softmax_half(sB, mB, lB, qB, qbaseB, &Ps[wid * 2 + 1][0], oaccB);

    asm volatile("s_waitcnt lgkmcnt(0)" ::: "memory");

    // O += P * V: one bv read feeds two MFMAs
    __builtin_amdgcn_s_setprio(1);
    for (int kk = 0; kk < 2; ++kk) {
      bf16x8 apA = *(const bf16x8*)(&Ps[wid * 2][r * 64 + (((kk * 4 + g) ^ (r & 7)) * 8)]);
      bf16x8 apB = *(const bf16x8*)(&Ps[wid * 2 + 1][r * 64 + (((kk * 4 + g) ^ (r & 7)) * 8)]);
      for (int dt = 0; dt < 8; ++dt) {
        int row = dt * 16 + r;
        bf16x8 bv = *(const bf16x8*)(&Vs[cur][row * 64 + (((kk * 4 + g) ^ (row & 7)) * 8)]);
        oaccA[dt] = __builtin_amdgcn_mfma_f32_16x16x32_bf16(apA, bv, oaccA[dt], 0, 0, 0);
        oaccB[dt] = __builtin_amdgcn_mfma_f32_16x16x32_bf16(apB, bv, oaccB[dt], 0, 0, 0);
      }
    }
    __builtin_amdgcn_s_setprio(0);
    __builtin_amdgcn_s_barrier();  // protect buf cur before overwrite at kt+2
  }

  // final: redistribute l to oacc row layout, write O (both fragments)
  float liA[4], liB[4];
  for (int e = 0; e < 4; ++e) {
    float lvA = __shfl(lA, (lane & 48) | (g * 4 + e), 64);
    float lvB = __shfl(lB, (lane & 48) | (g * 4 + e), 64);
    liA[e] = 1.f / lvA;
    liB[e] = 1.f / lvB;
  }
  for (int e = 0; e < 4; ++e) {
    const int growA = qbaseA + g * 4 + e;
    bf16* dstA = O + ((long)(b * T_ + growA)) * (NH_ * HD_) + h * HD_;
    for (int dt = 0; dt < 8; ++dt)
      dstA[dt * 16 + r] = (bf16)(oaccA[dt][e] * liA[e]);
    const int growB = qbaseB + g * 4 + e;
    bf16* dstB = O + ((long)(b * T_ + growB)) * (NH_ * HD_) + h * HD_;
    for (int dt = 0; dt < 8; ++dt)
      dstB[dt * 16 + r] = (bf16)(oaccB[dt][e] * liB[e]);
  }
}

extern "C" void kernel_launch(void* const* d_in, const int* in_sizes, int n_in,
                              void* d_out, int out_size, void* d_ws, size_t ws_size,
                              hipStream_t stream) {
  const float* x  = (const float*)d_in[0];
  const float* wq = (const float*)d_in[1];
  const float* wk = (const float*)d_in[2];
  const float* wv = (const float*)d_in[3];
  const float* wo = (const float*)d_in[4];
  const float* qw = (const float*)d_in[5];
  const float* kw = (const float*)d_in[6];
  float* out = (float*)d_out;

  char* p = (char*)d_ws;
  bf16* xb    = (bf16*)(p);                 // 16 MB  [4096][2048]
  bf16* wqkvb = (bf16*)(p + 16777216);      // 12 MB  [3072][2048] (wq|wk|wv)
  bf16* wob   = (bf16*)(p + 29360128);      //  8 MB  [2048][2048]
  bf16* QKVr  = (bf16*)(p + 37748736);      // 24 MB  [4096][3072]
  bf16* Qb    = (bf16*)(p + 62914560);      // 16 MB  [4096][2048]
  bf16* Kb    = (bf16*)(p + 79691776);      //  4 MB  [B][NKV][T][HD]
  bf16* Vt    = (bf16*)(p + 83886080);      //  4 MB  [B][NKV][HD][T]
  bf16* attb  = (bf16*)(p + 88080384);      // 16 MB  [4096][2048]

  cvt_all<<<18432, 256, 0, stream>>>(x, wq, wk, wv, wo, xb, wqkvb, wob);

  // fused QKV projection: [4096][2048] x [3072][2048]^T -> [4096][3072]
  gemm_bt<bf16><<<dim3(24, 32), 256, 0, stream>>>(xb, wqkvb, QKVr, 4096, 3072, 2048);

  norm_rope_qk<<<20480, 256, 0, stream>>>(QKVr, qw, kw, Qb, Kb);
  vpack<<<dim3(32, 16), 256, 0, stream>>>(QKVr, Vt);

  flash_attn<<<dim3(16, 16, 2), 256, 0, stream>>>(Qb, Kb, Vt, attb);

  gemm_bt<float><<<dim3(16, 32), 256, 0, stream>>>(attb, wob, out, 4096, 2048, 2048);
}

// Round 8
// 207.209 us; speedup vs baseline: 1.3283x; 1.3283x over previous
//
#include <hip/hip_runtime.h>
#include <hip/hip_bf16.h>

#define B_ 2
#define T_ 2048
#define D_ 2048
#define NH_ 16
#define NKV_ 4
#define HD_ 128

using bf16 = __bf16;
using bf16x8 = __attribute__((ext_vector_type(8))) __bf16;
using bf16x4 = __attribute__((ext_vector_type(4))) __bf16;
using f32x4 = __attribute__((ext_vector_type(4))) float;

__device__ __forceinline__ void gld_lds16(bf16* lds, const bf16* g) {
  __builtin_amdgcn_global_load_lds(
      (const __attribute__((address_space(1))) void*)g,
      (__attribute__((address_space(3))) void*)lds, 16, 0, 0);
}

// ---------------- fused f32 -> bf16 convert (all 5 tensors, 1 launch) ---------
// segments (in 256-thread blocks of float4): x 8192 | wq 4096 | wk 1024 | wv 1024 | wo 4096
__global__ __launch_bounds__(256) void cvt_all(const float* __restrict__ x,
                                               const float* __restrict__ wq,
                                               const float* __restrict__ wk,
                                               const float* __restrict__ wv,
                                               const float* __restrict__ wo,
                                               bf16* __restrict__ xb,
                                               bf16* __restrict__ wqkvb,
                                               bf16* __restrict__ wob) {
  const int bid = blockIdx.x;
  const float* src;
  bf16* dst;
  int base;
  if (bid < 8192)       { src = x;  dst = xb;              base = bid; }
  else if (bid < 12288) { src = wq; dst = wqkvb;           base = bid - 8192; }
  else if (bid < 13312) { src = wk; dst = wqkvb + 4194304; base = bid - 12288; }
  else if (bid < 14336) { src = wv; dst = wqkvb + 5242880; base = bid - 13312; }
  else                  { src = wo; dst = wob;             base = bid - 14336; }
  const int i = base * 256 + threadIdx.x;
  float4 v = ((const float4*)src)[i];
  bf16x4 o;
  o[0] = (bf16)v.x; o[1] = (bf16)v.y; o[2] = (bf16)v.z; o[3] = (bf16)v.w;
  ((bf16x4*)dst)[i] = o;
}

// ---------------- GEMM: C[M,N] = A[M,K] * Bt[N,K]^T ----------------
// 128x128 tile, BK=32, 256 threads (4 waves, 2x2), mfma 16x16x32 bf16.
// Triple-buffered LDS (48KB) + counted vmcnt(4) + raw s_barrier (1/K-step).
// Stage t+2 after barrier t; target buf (t-1)%3 safe (readers retired before
// the barrier). vmcnt(4) drains only stage(t), keeps stage(t+1) in flight.
// XCD-aware bijective block swizzle (grid size must be %8==0 — it is).
template<typename OutT>
__global__ __launch_bounds__(256) void gemm_bt(const bf16* __restrict__ A,
                                               const bf16* __restrict__ Bt,
                                               OutT* __restrict__ C,
                                               int M, int N, int K) {
  __shared__ bf16 As[3][128 * 32];
  __shared__ bf16 Bs[3][128 * 32];
  const int tid = threadIdx.x;
  const int wid = tid >> 6;
  const int lane = tid & 63;
  const int g = lane >> 4, r = lane & 15;
  const int wm = wid >> 1, wn = wid & 1;
  const int gx = gridDim.x;
  const int nwg = gx * gridDim.y;
  const int flat = blockIdx.y * gx + blockIdx.x;
  const int swz = (flat & 7) * (nwg >> 3) + (flat >> 3);
  const long bm = (long)(swz / gx) * 128, bn = (long)(swz % gx) * 128;
  f32x4 acc[4][4] = {};
  const int NT = K >> 5;

  auto stage = [&](int buf, int k0) {
    for (int c = 0; c < 2; ++c) {
      int ch = wid * 2 + c;
      int row = ch * 16 + (lane >> 2);
      int col = (lane & 3) * 8;
      gld_lds16(&As[buf][ch * 512], A + (bm + row) * K + k0 + col);
      gld_lds16(&Bs[buf][ch * 512], Bt + (bn + row) * K + k0 + col);
    }
  };

  stage(0, 0);
  stage(1, 32);
  for (int t = 0; t < NT; ++t) {
    if (t + 1 < NT)
      asm volatile("s_waitcnt vmcnt(4)" ::: "memory");  // stage(t) done, stage(t+1) in flight
    else
      asm volatile("s_waitcnt vmcnt(0)" ::: "memory");
    __builtin_amdgcn_s_barrier();
    if (t + 2 < NT) stage((t + 2) % 3, (t + 2) * 32);
    const bf16* as = As[t % 3];
    const bf16* bs = Bs[t % 3];
    bf16x8 af[4], bfr[4];
    for (int m = 0; m < 4; ++m)
      af[m] = *(const bf16x8*)(as + (wm * 64 + m * 16 + r) * 32 + g * 8);
    for (int n = 0; n < 4; ++n)
      bfr[n] = *(const bf16x8*)(bs + (wn * 64 + n * 16 + r) * 32 + g * 8);
    for (int m = 0; m < 4; ++m)
      for (int n = 0; n < 4; ++n)
        acc[m][n] = __builtin_amdgcn_mfma_f32_16x16x32_bf16(af[m], bfr[n], acc[m][n], 0, 0, 0);
  }

  for (int m = 0; m < 4; ++m)
    for (int n = 0; n < 4; ++n)
      for (int e = 0; e < 4; ++e) {
        long row = bm + wm * 64 + m * 16 + g * 4 + e;
        long col = bn + wn * 64 + n * 16 + r;
        C[row * N + col] = (OutT)acc[m][n][e];
      }
}

// ---------------- fused K RMSNorm+RoPE + V transpose (one launch) ----------------
// blocks [0,4096): K rows -> Kb [B][NKV][T][HD]; [4096,4608): V -> Vt [B][NKV][HD][T].
__global__ __launch_bounds__(256) void prep_kv(const bf16* __restrict__ qkv,
                                               const float* __restrict__ kw,
                                               bf16* __restrict__ Kb,
                                               bf16* __restrict__ Vt) {
  __shared__ float tile[64][65];
  const int bid = blockIdx.x;
  if (bid < 4096) {
    const int lane = threadIdx.x & 63;
    const int rloc = threadIdx.x >> 6;
    const long rid = (long)bid * 4 + rloc;
    const int h = (int)(rid % NKV_);
    const long bt = rid / NKV_;  // b*T + t
    const int t = (int)(bt % T_);
    const bf16* src = qkv + bt * 3072 + 2048 + h * HD_;
    float v0 = (float)src[lane];
    float v1 = (float)src[lane + 64];
    float ss = v0 * v0 + v1 * v1;
    for (int o = 1; o < 64; o <<= 1) ss += __shfl_xor(ss, o, 64);
    float inv = rsqrtf(ss * (1.f / HD_) + 1e-6f);
    float n0 = v0 * inv * kw[lane];
    float n1 = v1 * inv * kw[lane + 64];
    float ang = (float)t * exp2f((float)lane * (-13.287712379549449f / 64.f));
    float sv, cv;
    __sincosf(ang, &sv, &cv);
    long b = bt / T_;
    bf16* dst = Kb + ((b * NKV_ + h) * (long)T_ + t) * HD_;
    dst[lane] = (bf16)(n0 * cv - n1 * sv);
    dst[lane + 64] = (bf16)(n1 * cv + n0 * sv);
  } else {
    const int bid2 = bid - 4096;
    const int tt = bid2 & 31;
    const int by = bid2 >> 5;
    const int dd = by & 1;
    const int bkv = by >> 1;
    const long b = bkv >> 2;
    const int kv = bkv & 3;
    const int t0 = tt * 64, d0 = dd * 64;
    for (int i = 0; i < 2; ++i) {
      int row = i * 32 + (threadIdx.x >> 3);
      int c8 = (threadIdx.x & 7) * 8;
      bf16x8 v = *(const bf16x8*)&qkv[(b * T_ + t0 + row) * 3072 + 2560 + kv * HD_ + d0 + c8];
      for (int j = 0; j < 8; ++j) tile[row][c8 + j] = (float)v[j];
    }
    __syncthreads();
    for (int i = 0; i < 2; ++i) {
      int drow = i * 32 + (threadIdx.x >> 3);
      int tc8 = (threadIdx.x & 7) * 8;
      bf16x8 o;
      for (int j = 0; j < 8; ++j) o[j] = (bf16)tile[tc8 + j][drow];
      *(bf16x8*)&Vt[((b * NKV_ + kv) * (long)HD_ + d0 + drow) * T_ + t0 + tc8] = o;
    }
  }
}

// ---------------- causal GQA flash attention (swapped QK^T, per-lane softmax) ----
// Round-4/5 winner structure (8 waves / 128 q-rows, 80KB LDS, 16 waves/CU —
// the TLP resource two experiments showed is the binding constraint).
// Round 8: Q RMSNorm+RoPE fused into the prologue (reads QKVr directly,
// Qb buffer eliminated). Two-pass Q read keeps prologue VGPR low; cost is
// once-per-block, amortized over ~17 k-tiles.
// Anti-correlated qt pairing: co-resident pair (i, i+256) = same (x,y),
// opposite z; qt = z ? x : 15-x -> uniform 34 k-tile units per CU.
__global__ __launch_bounds__(512) void flash_attn(const bf16* __restrict__ QKV,
                                                  const float* __restrict__ qw,
                                                  const bf16* __restrict__ K,
                                                  const bf16* __restrict__ V,
                                                  bf16* __restrict__ O) {
  __shared__ bf16 Ks[2][64 * 128];   // [k][d], swizzled
  __shared__ bf16 Vs[2][128 * 64];   // [d][k], swizzled
  __shared__ bf16 Ps[8][16 * 64];    // per-wave P tile [q][k], swizzled
  const int h = blockIdx.y, b = blockIdx.z;
  const int qt = b ? blockIdx.x : (gridDim.x - 1) - blockIdx.x;  // pair long+short per CU
  const int kv = h >> 2;
  const int tid = threadIdx.x, wid = tid >> 6, lane = tid & 63;
  const int g = lane >> 4, r = lane & 15;
  const int q0 = qt * 128;
  const int qbase = q0 + wid * 16;      // wave-uniform
  const int q = qbase + r;              // this lane's q-row (softmax ownership)

  // ---- fused Q RMSNorm + RoPE prologue (replaces Qb round-trip) ----
  // lane holds dims kk*32+g*8+j; RoPE pairs (d, d+64) = (aq[0],aq[2]),(aq[1],aq[3]).
  const bf16* qsrc = QKV + ((long)(b * T_ + q)) * 3072 + h * HD_;
  float ss = 0.f;
  for (int kk = 0; kk < 4; ++kk) {
    bf16x8 tq = *(const bf16x8*)(qsrc + kk * 32 + g * 8);
    for (int j = 0; j < 8; ++j) { float f = (float)tq[j]; ss += f * f; }
  }
  ss += __shfl_xor(ss, 16, 64);
  ss += __shfl_xor(ss, 32, 64);
  const float inv = rsqrtf(ss * (1.f / HD_) + 1e-6f);
  bf16x8 aq[4];
  for (int kk = 0; kk < 2; ++kk) {
    bf16x8 tlo = *(const bf16x8*)(qsrc + kk * 32 + g * 8);        // L1-hot reload
    bf16x8 thi = *(const bf16x8*)(qsrc + kk * 32 + 64 + g * 8);
    bf16x8 alo, ahi;
    for (int j = 0; j < 8; ++j) {
      const int d = kk * 32 + g * 8 + j;
      float n0 = (float)tlo[j] * inv * qw[d];
      float n1 = (float)thi[j] * inv * qw[d + 64];
      float ang = (float)q * exp2f((float)d * (-13.287712379549449f / 64.f));
      float sv, cv;
      __sincosf(ang, &sv, &cv);
      alo[j] = (bf16)(n0 * cv - n1 * sv);
      ahi[j] = (bf16)(n1 * cv + n0 * sv);
    }
    aq[kk] = alo;
    aq[kk + 2] = ahi;
  }

  f32x4 oacc[8] = {};
  float m_run = -1e30f, l_run = 0.f;

  const bf16* Kbase = K + ((long)(b * NKV_ + kv)) * T_ * HD_;
  const bf16* Vbase = V + ((long)(b * NKV_ + kv)) * (long)HD_ * T_;
  const int nkt = 2 * qt + 2;

  // stage K (16 chunks of 1KB) + V^T (16 chunks): 2+2 chunks per wave
  auto stageKV = [&](int buf, int k0) {
    for (int c = 0; c < 2; ++c) {
      int ch = wid * 2 + c;
      {
        int row = ch * 4 + (lane >> 4);
        int srccol = ((lane & 15) ^ (row & 7)) * 8;
        gld_lds16(&Ks[buf][ch * 512], Kbase + (long)(k0 + row) * HD_ + srccol);
      }
      {
        int row = ch * 8 + (lane >> 3);
        int srccol = ((lane & 7) ^ (row & 7)) * 8;
        gld_lds16(&Vs[buf][ch * 512], Vbase + (long)row * T_ + k0 + srccol);
      }
    }
  };

  stageKV(0, 0);
  for (int kt = 0; kt < nkt; ++kt) {
    const int k0 = kt * 64;
    const int cur = kt & 1;
    if (kt + 1 < nkt) {
      stageKV(cur ^ 1, k0 + 64);
      asm volatile("s_waitcnt vmcnt(4)" ::: "memory");  // drain current tile only
    } else {
      asm volatile("s_waitcnt vmcnt(0)" ::: "memory");
    }
    __builtin_amdgcn_s_barrier();

    // S^T = K * Q^T : lane (g,r) holds S[k=k0+n*16+g*4+e][q]
    f32x4 s[4] = {};
    __builtin_amdgcn_s_setprio(1);
    for (int n = 0; n < 4; ++n)
      for (int kk = 0; kk < 4; ++kk) {
        int row = n * 16 + r;
        bf16x8 bk = *(const bf16x8*)(&Ks[cur][row * 128 + (((kk * 4 + g) ^ (row & 7)) * 8)]);
        s[n] = __builtin_amdgcn_mfma_f32_16x16x32_bf16(bk, aq[kk], s[n], 0, 0, 0);
      }
    __builtin_amdgcn_s_setprio(0);

    // per-lane softmax over 16 k-values
    const float scale = 0.088388347648318447f;  // 1/sqrt(128)
    const bool domask = (k0 + 63 > qbase);      // wave-uniform
    float mx = -1e30f;
    if (domask) {
      for (int n = 0; n < 4; ++n) {
        const int km = k0 + n * 16 + g * 4;
        for (int e = 0; e < 4; ++e) {
          float v = s[n][e] * scale;
          if (km + e > q) v = -1e30f;
          s[n][e] = v;
          mx = fmaxf(mx, v);
        }
      }
    } else {
      for (int n = 0; n < 4; ++n)
        for (int e = 0; e < 4; ++e) {
          float v = s[n][e] * scale;
          s[n][e] = v;
          mx = fmaxf(mx, v);
        }
    }
    mx = fmaxf(mx, __shfl_xor(mx, 16, 64));
    mx = fmaxf(mx, __shfl_xor(mx, 32, 64));
    float mnew = fmaxf(m_run, mx);
    float alpha = __expf(m_run - mnew);
    float ls = 0.f;
    for (int n = 0; n < 4; ++n) {
      bf16x4 pb;
      for (int e = 0; e < 4; ++e) {
        float p = __expf(s[n][e] - mnew);
        ls += p;
        pb[e] = (bf16)p;
      }
      int c = n * 2 + (g >> 1);
      *(bf16x4*)(&Ps[wid][r * 64 + ((c ^ (r & 7)) * 8) + (g & 1) * 4]) = pb;
    }
    ls += __shfl_xor(ls, 16, 64);
    ls += __shfl_xor(ls, 32, 64);
    m_run = mnew;
    l_run = l_run * alpha + ls;

    // broadcast alpha to oacc row layout (row = g*4+e held by lane with r==row)
    float al[4];
    for (int e = 0; e < 4; ++e)
      al[e] = __shfl(alpha, (lane & 48) | (g * 4 + e), 64);
    for (int dt = 0; dt < 8; ++dt)
      for (int e = 0; e < 4; ++e) oacc[dt][e] *= al[e];

    asm volatile("s_waitcnt lgkmcnt(0)" ::: "memory");

    // O += P * V
    __builtin_amdgcn_s_setprio(1);
    for (int kk = 0; kk < 2; ++kk) {
      bf16x8 ap = *(const bf16x8*)(&Ps[wid][r * 64 + (((kk * 4 + g) ^ (r & 7)) * 8)]);
      for (int dt = 0; dt < 8; ++dt) {
        int row = dt * 16 + r;
        bf16x8 bv = *(const bf16x8*)(&Vs[cur][row * 64 + (((kk * 4 + g) ^ (row & 7)) * 8)]);
        oacc[dt] = __builtin_amdgcn_mfma_f32_16x16x32_bf16(ap, bv, oacc[dt], 0, 0, 0);
      }
    }
    __builtin_amdgcn_s_setprio(0);
    __builtin_amdgcn_s_barrier();  // protect buf cur before overwrite at kt+2
  }

  // final: redistribute l to oacc row layout, write O
  float li[4];
  for (int e = 0; e < 4; ++e) {
    float lv = __shfl(l_run, (lane & 48) | (g * 4 + e), 64);
    li[e] = 1.f / lv;
  }
  for (int e = 0; e < 4; ++e) {
    const int grow = q0 + wid * 16 + g * 4 + e;
    bf16* dst = O + ((long)(b * T_ + grow)) * (NH_ * HD_) + h * HD_;
    for (int dt = 0; dt < 8; ++dt)
      dst[dt * 16 + r] = (bf16)(oacc[dt][e] * li[e]);
  }
}

extern "C" void kernel_launch(void* const* d_in, const int* in_sizes, int n_in,
                              void* d_out, int out_size, void* d_ws, size_t ws_size,
                              hipStream_t stream) {
  const float* x  = (const float*)d_in[0];
  const float* wq = (const float*)d_in[1];
  const float* wk = (const float*)d_in[2];
  const float* wv = (const float*)d_in[3];
  const float* wo = (const float*)d_in[4];
  const float* qw = (const float*)d_in[5];
  const float* kw = (const float*)d_in[6];
  float* out = (float*)d_out;

  char* p = (char*)d_ws;
  bf16* xb    = (bf16*)(p);                 // 16 MB  [4096][2048]
  bf16* wqkvb = (bf16*)(p + 16777216);      // 12 MB  [3072][2048] (wq|wk|wv)
  bf16* wob   = (bf16*)(p + 29360128);      //  8 MB  [2048][2048]
  bf16* QKVr  = (bf16*)(p + 37748736);      // 24 MB  [4096][3072]
  bf16* Kb    = (bf16*)(p + 79691776);      //  4 MB  [B][NKV][T][HD]
  bf16* Vt    = (bf16*)(p + 83886080);      //  4 MB  [B][NKV][HD][T]
  bf16* attb  = (bf16*)(p + 88080384);      // 16 MB  [4096][2048]

  cvt_all<<<18432, 256, 0, stream>>>(x, wq, wk, wv, wo, xb, wqkvb, wob);

  // fused QKV projection: [4096][2048] x [3072][2048]^T -> [4096][3072]
  gemm_bt<bf16><<<dim3(24, 32), 256, 0, stream>>>(xb, wqkvb, QKVr, 4096, 3072, 2048);

  prep_kv<<<4608, 256, 0, stream>>>(QKVr, kw, Kb, Vt);

  flash_attn<<<dim3(16, 16, 2), 512, 0, stream>>>(QKVr, qw, Kb, Vt, attb);

  gemm_bt<float><<<dim3(16, 32), 256, 0, stream>>>(attb, wob, out, 4096, 2048, 2048);
}